// Round 10
// baseline (328.187 us; speedup 1.0000x reference)
//
#include <hip/hip_runtime.h>
#include <hip/hip_bf16.h>

#define NN 200000
#define D 128
#define P 4096
#define R 4
#define T 3
#define K 16

__device__ __forceinline__ float bf2f(unsigned int u) {
    union { unsigned int i; float f; } c;
    c.i = u << 16;
    return c.f;
}
__device__ __forceinline__ unsigned short f2bf(float x) {  // RNE
    union { float f; unsigned int i; } c; c.f = x;
    unsigned int r = c.i + 0x7FFFu + ((c.i >> 16) & 1u);
    return (unsigned short)(r >> 16);
}
__device__ __forceinline__ float ldE(const void* p, size_t i, int f32) {
    return f32 ? ((const float*)p)[i] : bf2f(((const unsigned short*)p)[i]);
}
__device__ __forceinline__ void ld8(const void* p, size_t off, int f32, float* o) {
    if (f32) {
        const float* q = (const float*)p + off;
        float4 a = *(const float4*)q;
        float4 b = *(const float4*)(q + 4);
        o[0]=a.x; o[1]=a.y; o[2]=a.z; o[3]=a.w;
        o[4]=b.x; o[5]=b.y; o[6]=b.z; o[7]=b.w;
    } else {
        uint4 r = *(const uint4*)((const unsigned short*)p + off);
        o[0]=bf2f(r.x & 0xffffu); o[1]=bf2f(r.x >> 16);
        o[2]=bf2f(r.y & 0xffffu); o[3]=bf2f(r.y >> 16);
        o[4]=bf2f(r.z & 0xffffu); o[5]=bf2f(r.z >> 16);
        o[6]=bf2f(r.w & 0xffffu); o[7]=bf2f(r.w >> 16);
    }
}
__device__ __forceinline__ float readlane_f(float v, int lane) {
    return __int_as_float(__builtin_amdgcn_readlane(__float_as_int(v), lane));
}

// 16B per lane: global (per-lane scattered address) -> LDS base + lane*16.
// Defined BEFORE kernels; builtin only in the device pass (r9 fix: the host
// pass has no __builtin_amdgcn_global_load_lds and used to fail name lookup).
__device__ __forceinline__ void async_gather16(const void* gptr, void* ldsptr) {
#if defined(__HIP_DEVICE_COMPILE__) && __has_builtin(__builtin_amdgcn_global_load_lds)
    __builtin_amdgcn_global_load_lds(
        (const __attribute__((address_space(1))) void*)gptr,
        (__attribute__((address_space(3))) void*)ldsptr, 16, 0, 0);
#else
    const uint4 v = *(const uint4*)gptr;
    ((uint4*)ldsptr)[threadIdx.x & 63] = v;
#endif
}

// Prep: dtype detect (validated r2-r8) + v_t/u_t precompute. Grid = T x 128.
__global__ void prep_kernel(const unsigned short* __restrict__ emb_u,
                            const void* __restrict__ W_phi,
                            const void* __restrict__ W_zeta,
                            int* __restrict__ gflag,
                            float* __restrict__ ws_v, float* __restrict__ ws_u) {
    __shared__ int sbad[2];
    const int tid = threadIdx.x;          // 0..127
    const int t   = blockIdx.x;           // 0..T-1
    int bad = 0;
    #pragma unroll
    for (int i = 0; i < 4; ++i) {
        unsigned short u = emb_u[(size_t)(blockIdx.x * 512 + tid * 4 + i) * 2 * 97];
        unsigned int e = (u >> 7) & 0xFFu;
        if (e >= 147u) bad = 1;
    }
    int anyb = __any(bad) ? 1 : 0;
    if ((tid & 63) == 0) sbad[tid >> 6] = anyb;
    __syncthreads();
    const int f32 = sbad[0] | sbad[1];
    if (t == 0 && tid == 0) *gflag = f32;

    const int d = tid;
    const size_t rb = (size_t)(t * D + d) * D;
    float av = 0.f, au = 0.f;
    for (int e = 0; e < D; e += 8) {
        float w[8], zn[8], zs[8];
        ld8(W_phi, rb + e, f32, w);
        ld8(W_zeta, e, f32, zn);
        ld8(W_zeta, D + e, f32, zs);
        #pragma unroll
        for (int q = 0; q < 8; ++q) { av += w[q] * zn[q]; au += w[q] * zs[q]; }
    }
    ws_v[t * D + d] = av;
    ws_u[t * D + d] = au;
}

// Streaming per-node scores: c[n]=emb[n].v_{t(n)}, c2[n]=emb[n].u_{t(n)}.
__global__ __launch_bounds__(256) void precompute_c(
    const void* __restrict__ emb, const int* __restrict__ types,
    const float* __restrict__ ws_v, const float* __restrict__ ws_u,
    const int* __restrict__ flag,
    float* __restrict__ c, float* __restrict__ c2)
{
    __shared__ float vsh[T * D], ush[T * D];
    const int f32 = *flag;
    const int tid = threadIdx.x;
    for (int i = tid; i < T * D; i += 256) { vsh[i] = ws_v[i]; ush[i] = ws_u[i]; }
    __syncthreads();
    const int w = tid >> 6, l = tid & 63;
    const int grp = l >> 4, ch = l & 15;
    const int nbase = blockIdx.x * 64 + w * 4 + grp;

    int   tt[4];
    float rv[4][8];
    #pragma unroll
    for (int it = 0; it < 4; ++it) {
        int n = nbase + it * 16;
        tt[it] = types[n];
        ld8(emb, (size_t)n * D + ch * 8, f32, rv[it]);
    }
    #pragma unroll
    for (int it = 0; it < 4; ++it) {
        int n = nbase + it * 16;
        const float* vp = vsh + tt[it] * D + ch * 8;
        const float* up = ush + tt[it] * D + ch * 8;
        float a = 0.f, b = 0.f;
        #pragma unroll
        for (int q = 0; q < 8; ++q) { a += rv[it][q] * vp[q]; b += rv[it][q] * up[q]; }
        #pragma unroll
        for (int off = 1; off <= 8; off <<= 1) {
            a += __shfl_xor(a, off, 64);
            b += __shfl_xor(b, off, 64);
        }
        if (ch == 0) { c[n] = a; c2[n] = b; }
    }
}

// Fused hot kernel: block = 1 pair x 2 side-waves (128 thr).
// Stage: each wave issues 16 async global->LDS 1KB gathers (side-effecting
// intrinsic -- compiler cannot sink/serialize them; zero data VGPRs).
// Phase 1 alpha (r7-verified) overlaps the staging drain. Consume from LDS.
__global__ __launch_bounds__(128, 2) void fused_all(
    const void* __restrict__ emb,               // (N,D)
    const int* __restrict__ pairs,              // (P,2)
    const int* __restrict__ nbr,                // (P,2,R,K)
    const void* __restrict__ dlt,               // (P,2,R,K)
    const void* __restrict__ W_bw,              // (R,D,D)
    const void* __restrict__ W_bb,              // (R,D)
    const float* __restrict__ c,                // (N,)
    const float* __restrict__ c2,               // (N,)
    const int* __restrict__ flag,
    void* __restrict__ out)                     // (P,D)
{
    __shared__ __align__(16) unsigned short srow[2][R * K][D]; // 32 KB raw bf16 rows
    __shared__ __align__(16) unsigned short gshb[2][R][D];     // 2 KB bf16 g
    __shared__ __align__(16) float ysh[2][D];                  // 1 KB

    const int f32  = *flag;
    const int tid  = threadIdx.x;               // 0..127
    const int s    = tid >> 6;                  // side = wave
    const int l    = tid & 63;
    const int p    = blockIdx.x;
    const int rsub = l >> 4;
    const int ch   = l & 15;
    const int base = p * 2 * R * K + s * 64;    // flat (p,s,0,0)

    // Row ownership for phase 1: lane j owns row j (r=j>>4, k=j&15).
    const int nb = nbr[base + l];

    if (!f32) {
        const unsigned short* eu = (const unsigned short*)emb;
        // ---- Stage: 16 async 1KB gathers; instr t covers rows 4t..4t+3.
        // Lane l fetches 16B chunk (l&15) of row 4t+(l>>4); lands at
        // LDS base + l*16 = row 4t+(l>>4), chunk l&15. Layout matches.
        #pragma unroll
        for (int t = 0; t < 16; ++t) {
            int nbq = __shfl(nb, t * 4 + (l >> 4), 64);
            async_gather16(eu + (size_t)nbq * D + ch * 8, &srow[s][t * 4][0]);
        }
    }

    // ---- Phase 1 (overlaps staging drain): alpha for row j=l.
    const float dt = ldE(dlt, (size_t)base + l, f32);
    const float ce = c[nb];
    const float es = c2[pairs[p * 2 + s]];
    float e = (ce + es) * __expf(-dt);
    float m = e;
    #pragma unroll
    for (int off = 1; off <= 8; off <<= 1) m = fmaxf(m, __shfl_xor(m, off, 64));
    float al = __expf(e - m);
    float ssum = al;
    #pragma unroll
    for (int off = 1; off <= 8; off <<= 1) ssum += __shfl_xor(ssum, off, 64);
    al *= (1.f / ssum);

    if (!f32) {
        __syncthreads();   // drains vmcnt(0): all staged rows visible
        // ---- Consume: lane l owns dword l (elems 2l,2l+1) of every row.
        // ds_read_b32: 64 lanes -> 64 consecutive dwords = 2/bank = free (m136).
        #pragma unroll
        for (int r = 0; r < R; ++r) {
            float a0 = 0.f, a1 = 0.f;
            #pragma unroll
            for (int k = 0; k < K; ++k) {
                float a = readlane_f(al, r * K + k);     // compile-time lane -> SGPR
                unsigned int d2 = *(const unsigned int*)&srow[s][r * K + k][2 * l];
                a0 += a * bf2f(d2 & 0xffffu);
                a1 += a * bf2f(d2 >> 16);
            }
            *(unsigned int*)&gshb[s][r][2 * l] =
                (unsigned int)f2bf(a0) | ((unsigned int)f2bf(a1) << 16);
        }
    } else {
        // fp32 fallback (r8-verified shape): direct register gather.
        const float* efp = (const float*)emb;
        #pragma unroll
        for (int r = 0; r < R; ++r) {
            int snb[4]; float av4[4];
            #pragma unroll
            for (int i = 0; i < 4; ++i) {
                int srcl = r * 16 + i * 4 + rsub;
                snb[i] = __shfl(nb, srcl, 64);
                av4[i] = __shfl(al, srcl, 64);
            }
            float acc[8] = {0.f,0.f,0.f,0.f,0.f,0.f,0.f,0.f};
            #pragma unroll
            for (int i = 0; i < 4; ++i) {
                float4 r0 = *(const float4*)(efp + (size_t)snb[i] * D + ch * 8);
                float4 r1 = *(const float4*)(efp + (size_t)snb[i] * D + ch * 8 + 4);
                float a = av4[i];
                acc[0] += a * r0.x; acc[1] += a * r0.y; acc[2] += a * r0.z; acc[3] += a * r0.w;
                acc[4] += a * r1.x; acc[5] += a * r1.y; acc[6] += a * r1.z; acc[7] += a * r1.w;
            }
            #pragma unroll
            for (int q = 0; q < 8; ++q) {
                acc[q] += __shfl_xor(acc[q], 16, 64);
                acc[q] += __shfl_xor(acc[q], 32, 64);
            }
            if (rsub == 0) {
                #pragma unroll
                for (int q = 0; q < 4; ++q)
                    *(unsigned int*)&gshb[s][r][ch * 8 + 2 * q] =
                        (unsigned int)f2bf(acc[2 * q]) | ((unsigned int)f2bf(acc[2 * q + 1]) << 16);
            }
        }
    }
    __syncthreads();

    // ---- Beta matvec (verified r6-r8): wave s handles r in {2s, 2s+1}.
    float y[8] = {0.f,0.f,0.f,0.f,0.f,0.f,0.f,0.f};
    const unsigned short* Wu = (const unsigned short*)W_bw;
    #pragma unroll
    for (int rr = 0; rr < 2; ++rr) {
        const int r = s * 2 + rr;
        #pragma unroll 8
        for (int dd = 0; dd < 32; ++dd) {
            const int d = rsub * 32 + dd;
            float gd = bf2f(gshb[0][r][d]) + bf2f(gshb[1][r][d]);
            size_t wo = ((size_t)(r * D + d)) * D + ch * 8;
            if (!f32) {
                uint4 wr = *(const uint4*)(Wu + wo);
                y[0] += gd * bf2f(wr.x & 0xffffu); y[1] += gd * bf2f(wr.x >> 16);
                y[2] += gd * bf2f(wr.y & 0xffffu); y[3] += gd * bf2f(wr.y >> 16);
                y[4] += gd * bf2f(wr.z & 0xffffu); y[5] += gd * bf2f(wr.z >> 16);
                y[6] += gd * bf2f(wr.w & 0xffffu); y[7] += gd * bf2f(wr.w >> 16);
            } else {
                float wb[8]; ld8(W_bw, wo, 1, wb);
                #pragma unroll
                for (int q = 0; q < 8; ++q) y[q] += gd * wb[q];
            }
        }
    }
    #pragma unroll
    for (int q = 0; q < 8; ++q) {
        y[q] += __shfl_xor(y[q], 16, 64);
        y[q] += __shfl_xor(y[q], 32, 64);
    }
    if (rsub == 0) {
        *(float4*)(&ysh[s][ch * 8])     = make_float4(y[0], y[1], y[2], y[3]);
        *(float4*)(&ysh[s][ch * 8 + 4]) = make_float4(y[4], y[5], y[6], y[7]);
    }
    __syncthreads();

    // ---- Epilogue (verified r6-r8): s==0, rsub==0 lanes store the 256B row.
    if (s == 0 && rsub == 0) {
        float bs[8] = {0.f,0.f,0.f,0.f,0.f,0.f,0.f,0.f};
        #pragma unroll
        for (int r = 0; r < R; ++r) {
            float bb[8]; ld8(W_bb, (size_t)r * D + ch * 8, f32, bb);
            #pragma unroll
            for (int q = 0; q < 8; ++q) bs[q] += bb[q];
        }
        float o[8];
        #pragma unroll
        for (int q = 0; q < 8; ++q) {
            int e2 = ch * 8 + q;
            float x = (ysh[0][e2] + ysh[1][e2] + 2.f * bs[q]) * 0.125f;
            o[q] = 1.f / (1.f + __expf(-x));
        }
        size_t ob = (size_t)p * D + ch * 8;
        if (f32) {
            *(float4*)((float*)out + ob)     = make_float4(o[0], o[1], o[2], o[3]);
            *(float4*)((float*)out + ob + 4) = make_float4(o[4], o[5], o[6], o[7]);
        } else {
            uint4 pk;
            pk.x = (unsigned int)f2bf(o[0]) | ((unsigned int)f2bf(o[1]) << 16);
            pk.y = (unsigned int)f2bf(o[2]) | ((unsigned int)f2bf(o[3]) << 16);
            pk.z = (unsigned int)f2bf(o[4]) | ((unsigned int)f2bf(o[5]) << 16);
            pk.w = (unsigned int)f2bf(o[6]) | ((unsigned int)f2bf(o[7]) << 16);
            *(uint4*)((unsigned short*)out + ob) = pk;
        }
    }
}

extern "C" void kernel_launch(void* const* d_in, const int* in_sizes, int n_in,
                              void* d_out, int out_size, void* d_ws, size_t ws_size,
                              hipStream_t stream) {
    const void* emb    = d_in[0];
    const int*  pairs  = (const int*)d_in[1];
    const int*  types  = (const int*)d_in[2];
    const int*  nbr    = (const int*)d_in[3];
    const void* dlt    = d_in[4];
    const void* W_phi  = d_in[5];
    const void* W_zeta = d_in[6];
    const void* W_bw   = d_in[7];
    const void* W_bb   = d_in[8];

    int*   flag = (int*)d_ws;                        // bytes [0,256)
    float* ws_v = (float*)d_ws + 64;                 // 384 floats
    float* ws_u = ws_v + T * D;                      // 384 floats
    float* c    = (float*)d_ws + 1024;               // N floats
    float* c2   = c + NN;                            // N floats (~1.6 MB total)

    prep_kernel<<<dim3(T), dim3(128), 0, stream>>>((const unsigned short*)emb,
                                                   W_phi, W_zeta, flag, ws_v, ws_u);
    precompute_c<<<dim3(NN / 64), dim3(256), 0, stream>>>(emb, types, ws_v, ws_u,
                                                          flag, c, c2);
    fused_all<<<dim3(P), dim3(128), 0, stream>>>(emb, pairs, nbr, dlt,
                                                 W_bw, W_bb, c, c2, flag, d_out);
}

// Round 11
// 259.469 us; speedup vs baseline: 1.2648x; 1.2648x over previous
//
#include <hip/hip_runtime.h>
#include <hip/hip_bf16.h>

#define NN 200000
#define D 128
#define P 4096
#define R 4
#define T 3
#define K 16

__device__ __forceinline__ float bf2f(unsigned int u) {
    union { unsigned int i; float f; } c;
    c.i = u << 16;
    return c.f;
}
__device__ __forceinline__ unsigned short f2bf(float x) {  // RNE
    union { float f; unsigned int i; } c; c.f = x;
    unsigned int r = c.i + 0x7FFFu + ((c.i >> 16) & 1u);
    return (unsigned short)(r >> 16);
}
__device__ __forceinline__ float ldE(const void* p, size_t i, int f32) {
    return f32 ? ((const float*)p)[i] : bf2f(((const unsigned short*)p)[i]);
}
__device__ __forceinline__ void ld8(const void* p, size_t off, int f32, float* o) {
    if (f32) {
        const float* q = (const float*)p + off;
        float4 a = *(const float4*)q;
        float4 b = *(const float4*)(q + 4);
        o[0]=a.x; o[1]=a.y; o[2]=a.z; o[3]=a.w;
        o[4]=b.x; o[5]=b.y; o[6]=b.z; o[7]=b.w;
    } else {
        uint4 r = *(const uint4*)((const unsigned short*)p + off);
        o[0]=bf2f(r.x & 0xffffu); o[1]=bf2f(r.x >> 16);
        o[2]=bf2f(r.y & 0xffffu); o[3]=bf2f(r.y >> 16);
        o[4]=bf2f(r.z & 0xffffu); o[5]=bf2f(r.z >> 16);
        o[6]=bf2f(r.w & 0xffffu); o[7]=bf2f(r.w >> 16);
    }
}

// Prep: dtype detect (validated r2-r10) + v_t/u_t precompute. Grid = T x 128.
__global__ void prep_kernel(const unsigned short* __restrict__ emb_u,
                            const void* __restrict__ W_phi,
                            const void* __restrict__ W_zeta,
                            int* __restrict__ gflag,
                            float* __restrict__ ws_v, float* __restrict__ ws_u) {
    __shared__ int sbad[2];
    const int tid = threadIdx.x;          // 0..127
    const int t   = blockIdx.x;           // 0..T-1
    int bad = 0;
    #pragma unroll
    for (int i = 0; i < 4; ++i) {
        unsigned short u = emb_u[(size_t)(blockIdx.x * 512 + tid * 4 + i) * 2 * 97];
        unsigned int e = (u >> 7) & 0xFFu;
        if (e >= 147u) bad = 1;
    }
    int anyb = __any(bad) ? 1 : 0;
    if ((tid & 63) == 0) sbad[tid >> 6] = anyb;
    __syncthreads();
    const int f32 = sbad[0] | sbad[1];
    if (t == 0 && tid == 0) *gflag = f32;

    const int d = tid;
    const size_t rb = (size_t)(t * D + d) * D;
    float av = 0.f, au = 0.f;
    for (int e = 0; e < D; e += 8) {
        float w[8], zn[8], zs[8];
        ld8(W_phi, rb + e, f32, w);
        ld8(W_zeta, e, f32, zn);
        ld8(W_zeta, D + e, f32, zs);
        #pragma unroll
        for (int q = 0; q < 8; ++q) { av += w[q] * zn[q]; au += w[q] * zs[q]; }
    }
    ws_v[t * D + d] = av;
    ws_u[t * D + d] = au;
}

// Per-node scores, ROW PER THREAD (r10 rewrite): full 128-dot in registers,
// zero cross-lane ops (the old shuffle chains were the latency cost).
// v/u LDS tables padded to stride 129: t*129 spreads the 3 type-rows across
// banks so the 64-lane broadcast reads are conflict-free.
__global__ __launch_bounds__(256) void precompute_c(
    const void* __restrict__ emb, const int* __restrict__ types,
    const float* __restrict__ ws_v, const float* __restrict__ ws_u,
    const int* __restrict__ flag,
    float* __restrict__ c, float* __restrict__ c2)
{
    __shared__ float vsh[T * 129], ush[T * 129];
    const int f32 = *flag;
    const int tid = threadIdx.x;
    for (int i = tid; i < T * D; i += 256) {
        int t = i >> 7, d = i & 127;
        vsh[t * 129 + d] = ws_v[i];
        ush[t * 129 + d] = ws_u[i];
    }
    __syncthreads();
    const int n = blockIdx.x * 256 + tid;
    if (n >= NN) return;
    const int t = types[n];
    const float* vp = vsh + t * 129;
    const float* up = ush + t * 129;
    float a = 0.f, b = 0.f;
    #pragma unroll 4
    for (int j = 0; j < D; j += 8) {
        float rv[8]; ld8(emb, (size_t)n * D + j, f32, rv);
        #pragma unroll
        for (int q = 0; q < 8; ++q) { a += rv[q] * vp[j + q]; b += rv[q] * up[j + q]; }
    }
    c[n] = a;
    c2[n] = b;
}

// Fused kernel (r3-verified, 76us @ ~2.0 TB/s = ~92% of the measured random-
// 256B-granule pattern ceiling): one block per pair; alpha-first from the
// c-tables; uint4 quarter-wave row bursts issued before the score/softmax
// barriers; in-kernel beta matvec + sigmoid epilogue.
__global__ __launch_bounds__(256, 4) void fused_kernel(
    const void* __restrict__ emb,               // (N,D)
    const int* __restrict__ pairs,              // (P,2)
    const int* __restrict__ nbr,                // (P,2,R,K)
    const void* __restrict__ dlt,               // (P,2,R,K)
    const void* __restrict__ W_beta_w,          // (R,D,D)
    const void* __restrict__ W_beta_b,          // (R,D)
    const float* __restrict__ c,                // (N,)
    const float* __restrict__ c2,               // (N,)
    const int* __restrict__ flag,
    void* __restrict__ out)                     // (P,D)
{
    __shared__ float esc[128];                  // e scores, then alpha in place
    __shared__ __align__(16) float gbuf[4 * D];
    __shared__ __align__(16) float ybuf[4 * D];

    const int f32  = *flag;
    const int p    = blockIdx.x;
    const int tid  = threadIdx.x;
    const int w    = tid >> 6;                  // wave = r
    const int l    = tid & 63;
    const int rsub = l >> 4;                    // row-in-quad / d-quarter
    const int ch   = l & 15;                    // 8-elem chunk
    const int base = p * 2 * R * K;

    // --- Prefetch (bf16 fast path): issue all row gathers NOW; they drain
    // behind the score/softmax phases. jj = s*64 + w*16 + k, k=(i&3)*4+rsub.
    int  nbv[8];
    uint4 rb[8];
    if (!f32) {
        const unsigned short* eu = (const unsigned short*)emb;
        #pragma unroll
        for (int i = 0; i < 8; ++i) {
            int jj = ((i >> 2) * 64) + w * 16 + (i & 3) * 4 + rsub;
            nbv[i] = nbr[base + jj];
        }
        #pragma unroll
        for (int i = 0; i < 8; ++i)
            rb[i] = *(const uint4*)(eu + (size_t)nbv[i] * D + ch * 8);
    }

    // --- Phase A: scores e = (c[nb] + c2[pair_s]) * exp(-dt)
    if (tid < 128) {
        int s  = tid >> 6;
        int nb = nbr[base + tid];
        float ce = c[nb];
        float cs = c2[pairs[p * 2 + s]];
        float dt = ldE(dlt, (size_t)base + tid, f32);
        esc[tid] = (ce + cs) * __expf(-dt);
    }
    __syncthreads();

    // --- Phase B: softmax over K per group, in place
    if (tid < 8) {
        float ev[K];
        float mx = -1e30f;
        #pragma unroll
        for (int k = 0; k < K; ++k) { ev[k] = esc[tid * K + k]; mx = fmaxf(mx, ev[k]); }
        float sum = 0.f;
        #pragma unroll
        for (int k = 0; k < K; ++k) { ev[k] = __expf(ev[k] - mx); sum += ev[k]; }
        float inv = 1.f / sum;
        #pragma unroll
        for (int k = 0; k < K; ++k) esc[tid * K + k] = ev[k] * inv;
    }
    __syncthreads();

    // --- Phase C: g_r[d] = sum_{s,k} alpha * emb[nb][d]  (wave w -> r=w)
    float acc[8] = {0.f,0.f,0.f,0.f,0.f,0.f,0.f,0.f};
    if (!f32) {
        float al[8];
        #pragma unroll
        for (int i = 0; i < 8; ++i) {
            int jj = ((i >> 2) * 64) + w * 16 + (i & 3) * 4 + rsub;
            al[i] = esc[jj];
        }
        #pragma unroll
        for (int i = 0; i < 8; ++i) {
            float a = al[i];
            acc[0] += a * bf2f(rb[i].x & 0xffffu); acc[1] += a * bf2f(rb[i].x >> 16);
            acc[2] += a * bf2f(rb[i].y & 0xffffu); acc[3] += a * bf2f(rb[i].y >> 16);
            acc[4] += a * bf2f(rb[i].z & 0xffffu); acc[5] += a * bf2f(rb[i].z >> 16);
            acc[6] += a * bf2f(rb[i].w & 0xffffu); acc[7] += a * bf2f(rb[i].w >> 16);
        }
    } else {
        #pragma unroll
        for (int i = 0; i < 8; ++i) {
            int jj = ((i >> 2) * 64) + w * 16 + (i & 3) * 4 + rsub;
            int nb = nbr[base + jj];
            float a = esc[jj];
            float rv[8]; ld8(emb, (size_t)nb * D + ch * 8, 1, rv);
            #pragma unroll
            for (int q = 0; q < 8; ++q) acc[q] += a * rv[q];
        }
    }
    #pragma unroll
    for (int q = 0; q < 8; ++q) {
        acc[q] += __shfl_xor(acc[q], 16, 64);
        acc[q] += __shfl_xor(acc[q], 32, 64);
    }
    if (rsub == 0) {
        *(float4*)(gbuf + w * D + ch * 8)     = make_float4(acc[0], acc[1], acc[2], acc[3]);
        *(float4*)(gbuf + w * D + ch * 8 + 4) = make_float4(acc[4], acc[5], acc[6], acc[7]);
    }
    __syncthreads();

    // --- Phase D: y_r[e] = sum_d g_r[d] * W[r,d,e]; 16B/lane coalesced loads.
    {
        const int dq = rsub;                     // d-quarter 0..3
        float y[8] = {0.f,0.f,0.f,0.f,0.f,0.f,0.f,0.f};
        #pragma unroll 4
        for (int dd = 0; dd < 32; ++dd) {
            int d = dq * 32 + dd;
            float gd = gbuf[w * D + d];
            float wb[8]; ld8(W_beta_w, ((size_t)(w * D + d)) * D + ch * 8, f32, wb);
            #pragma unroll
            for (int q = 0; q < 8; ++q) y[q] += gd * wb[q];
        }
        #pragma unroll
        for (int q = 0; q < 8; ++q) {
            y[q] += __shfl_xor(y[q], 16, 64);
            y[q] += __shfl_xor(y[q], 32, 64);
        }
        if (dq == 0) {
            *(float4*)(ybuf + w * D + ch * 8)     = make_float4(y[0], y[1], y[2], y[3]);
            *(float4*)(ybuf + w * D + ch * 8 + 4) = make_float4(y[4], y[5], y[6], y[7]);
        }
    }
    __syncthreads();

    // --- Phase E: combine, bias, sigmoid, store
    if (tid < 128) {
        int e = tid;
        float x = ybuf[e] + ybuf[D + e] + ybuf[2 * D + e] + ybuf[3 * D + e];
        float bs = 0.f;
        #pragma unroll
        for (int r = 0; r < R; ++r) bs += ldE(W_beta_b, r * D + e, f32);
        x = (x + 2.f * bs) * 0.125f;
        float o = 1.f / (1.f + __expf(-x));
        size_t oi = (size_t)p * D + e;
        if (f32) ((float*)out)[oi] = o;
        else     ((unsigned short*)out)[oi] = f2bf(o);
    }
}

extern "C" void kernel_launch(void* const* d_in, const int* in_sizes, int n_in,
                              void* d_out, int out_size, void* d_ws, size_t ws_size,
                              hipStream_t stream) {
    const void* emb    = d_in[0];
    const int*  pairs  = (const int*)d_in[1];
    const int*  types  = (const int*)d_in[2];
    const int*  nbr    = (const int*)d_in[3];
    const void* dlt    = d_in[4];
    const void* W_phi  = d_in[5];
    const void* W_zeta = d_in[6];
    const void* W_bw   = d_in[7];
    const void* W_bb   = d_in[8];

    int*   flag = (int*)d_ws;                        // bytes [0,256)
    float* ws_v = (float*)d_ws + 64;                 // 384 floats
    float* ws_u = ws_v + T * D;                      // 384 floats
    float* c    = (float*)d_ws + 1024;               // N floats
    float* c2   = c + NN;                            // N floats (~1.6 MB total)

    prep_kernel<<<dim3(T), dim3(128), 0, stream>>>((const unsigned short*)emb,
                                                   W_phi, W_zeta, flag, ws_v, ws_u);
    precompute_c<<<dim3((NN + 255) / 256), dim3(256), 0, stream>>>(emb, types, ws_v, ws_u,
                                                                   flag, c, c2);
    fused_kernel<<<dim3(P), dim3(256), 0, stream>>>(emb, pairs, nbr, dlt,
                                                    W_bw, W_bb, c, c2, flag, d_out);
}